// Round 13
// baseline (571.931 us; speedup 1.0000x reference)
//
#include <hip/hip_runtime.h>

// LiquidNeuralNetwork: B=512, S=1024, IN=16, HID=64, OUT=1.
// Established (r0-r12): serial-latency-bound, wall ~ 5 cyc/inst x insts on
// the ONE serial wave per chain; absmax pinned at 2^-16 (f16 weight floor)
// across RK4x4 -> RK4x1 -> RK2 -> expEuler. r12 = 345us dispatch at ~106
// insts/step (proj 20 + odot/allsum 15 + eval 57 + glue).
//
// Round 13: only h_s -> h_{s+1} is sequential. Move everything else off the
// serial wave:
//   K1 (parallel): cb[b][s][i] = beta_i*(Wc.x+cbase) for all (b,s) -> ws
//       (same fma tree as r12 -> bit-identical c).
//   K2 (serial):   per step: {cb depth-3 reg prefetch, tanh, gather, 32
//       fdot, comb4, store t (f16, reuses gather's cvt), h = a*h + f}
//       ~70 insts/step. No proj, no output dot, no x at all.
//   K3 (parallel): out[b][s] = bo + sum_i wov_i * t[b][s][i] via __shfl_xor
//       wave reduce.
// ws need = 128MB (cb) + 64MB (t) = 192MB; if ws_size smaller -> launch the
// proven r12 kernel unchanged. Discovery-verified swap-combine (M0/M1/M2) +
// LDS-broadcast fallback kept in K2.

constexpr int HID  = 64;
constexpr int INF  = 16;
constexpr int SLEN = 1024;
constexpr int BATCH = 512;

typedef __fp16 h2_t __attribute__((ext_vector_type(2)));
typedef unsigned u32x2_t __attribute__((ext_vector_type(2)));

template<int CTRL>
__device__ __forceinline__ unsigned dppmov(unsigned v) {
    return (unsigned)__builtin_amdgcn_update_dpp(0, (int)v, CTRL, 0xF, 0xF, true);
}

__device__ __forceinline__ float fdot(unsigned a, h2_t w, float acc) {
    return __builtin_amdgcn_fdot2(__builtin_bit_cast(h2_t, a), w, acc, false);
}

__device__ __forceinline__ float fast_tanh(float x) {
    // tanh(x) = 1 - 2/(e^{2x}+1); exact limits at +/-inf, no clamp needed.
    float e = __builtin_amdgcn_exp2f(x * 2.8853900817779268f); // 2*log2(e)
    float r = __builtin_amdgcn_rcpf(e + 1.0f);
    return fmaf(-2.0f, r, 1.0f);
}

// -expm1(-z) by series, exact to ~1e-17 for z ~ 1e-3 (avoids 1-exp cancel)
__device__ __forceinline__ float beta_of(float z) {
    return z * (1.0f - z * (0.5f - z * ((1.0f/6.0f) - z * (1.0f/24.0f))));
}

// In-group all-gather: lane l ends with all 16 values of its 16-lane group
// as 8 h2 regs, lane-dependent order (discovered at setup).
__device__ __forceinline__ void gatherG(float t, unsigned g[8]) {
    unsigned th = (unsigned)__builtin_bit_cast(unsigned short, (__fp16)t);
    unsigned tp = dppmov<0xB1>(th);            // quad_perm [1,0,3,2] = ^1
    g[0] = (tp << 16) | th;                    // h2 {self, ^1}
    g[1] = dppmov<0x4E>(g[0]);                 // quad_perm [2,3,0,1] = ^2
    g[2] = dppmov<0x141>(g[0]);                // row_half_mirror = ^7
    g[3] = dppmov<0x141>(g[1]);
    g[4] = dppmov<0x128>(g[0]);                // row_ror:8 = ^8
    g[5] = dppmov<0x128>(g[1]);
    g[6] = dppmov<0x128>(g[2]);
    g[7] = dppmov<0x128>(g[3]);
}

// pair swaps: returns both modified regs (float payloads)
__device__ __forceinline__ u32x2_t sw32(float a, float b) {
    return __builtin_amdgcn_permlane32_swap(__builtin_bit_cast(unsigned, a),
                                            __builtin_bit_cast(unsigned, b),
                                            false, false);
}
__device__ __forceinline__ u32x2_t sw16(float a, float b) {
    return __builtin_amdgcn_permlane16_swap(__builtin_bit_cast(unsigned, a),
                                            __builtin_bit_cast(unsigned, b),
                                            false, false);
}
__device__ __forceinline__ float sum2(u32x2_t r) {
    return __builtin_bit_cast(float, r[0]) + __builtin_bit_cast(float, r[1]);
}

// =========================================================================
// K1: input projection, fully parallel. cb[b][s][i] = beta_i*(Wc_i . x + cb)
// =========================================================================
__global__ __launch_bounds__(256) void lnn_proj_kernel(
    const float* __restrict__ x,
    const float* __restrict__ W_in,
    const float* __restrict__ b_in,
    const float* __restrict__ W_ih,
    const float* __restrict__ bias,
    const float* __restrict__ tau,
    float* __restrict__ cb)
{
    const int b     = blockIdx.x;
    const int sbase = blockIdx.y * 128;
    const int lane  = threadIdx.x & 63;
    const int srow  = threadIdx.x >> 6;      // 0..3

    float Wc[INF];
    #pragma unroll
    for (int k = 0; k < INF; ++k) Wc[k] = 0.0f;
    float bcomb = 0.0f;
    for (int j = 0; j < HID; ++j) {
        float wij = W_ih[lane * HID + j];
        bcomb = fmaf(wij, b_in[j], bcomb);
        #pragma unroll
        for (int k = 0; k < INF; ++k) Wc[k] = fmaf(wij, W_in[j * INF + k], Wc[k]);
    }
    const float cbase = bcomb + bias[lane];
    const float hsub  = 1.0f / 1023.0f;
    const float rtau  = 1.0f / tau[lane];
    const float beta  = beta_of(hsub * rtau);

    for (int it = 0; it < 32; ++it) {
        int s = sbase + it * 4 + srow;
        const float4* xs = (const float4*)(x + ((size_t)b * SLEN + s) * INF);
        float4 p0 = xs[0], p1 = xs[1], p2 = xs[2], p3 = xs[3];
        float cA = fmaf(p0.x, Wc[0], fmaf(p0.y, Wc[1],
                   fmaf(p0.z, Wc[2], fmaf(p0.w, Wc[3], cbase))));
        float cB = fmaf(p1.x, Wc[4], fmaf(p1.y, Wc[5],
                   fmaf(p1.z, Wc[6], p1.w * Wc[7])));
        float cC = fmaf(p2.x, Wc[8], fmaf(p2.y, Wc[9],
                   fmaf(p2.z, Wc[10], p2.w * Wc[11])));
        float cD = fmaf(p3.x, Wc[12], fmaf(p3.y, Wc[13],
                   fmaf(p3.z, Wc[14], p3.w * Wc[15])));
        cb[((size_t)b * SLEN + s) * HID + lane] = ((cA + cB) + (cC + cD)) * beta;
    }
}

// =========================================================================
// K2: the serial chain. Reads cb, writes t (f16). ~70 insts/step.
// =========================================================================
__global__ __launch_bounds__(64, 1) void lnn_chain_ws_kernel(
    const float* __restrict__ cb,
    __fp16* __restrict__ tws,
    const float* __restrict__ W_hh,
    const float* __restrict__ tau)
{
    const int lane = threadIdx.x;        // hidden index
    const int b    = blockIdx.x;         // batch index

    __shared__ __fp16 th_s[HID];         // fallback path only

    const float hsub  = 1.0f / 1023.0f;
    const float rtau  = 1.0f / tau[lane];
    const float beta  = beta_of(hsub * rtau);
    const float alpha = 1.0f - beta;

    const float* cbp = cb  + (size_t)b * SLEN * HID + lane;
    __fp16*      tp  = tws + (size_t)b * SLEN * HID + lane;

    // --- discovery: in-group gather order -----------------------------------
    unsigned gd[8];
    gatherG((float)lane, gd);            // payload = lane index, exact in f16
    int e0[8], e1[8];
    unsigned covm = 0;
    #pragma unroll
    for (int r = 0; r < 8; ++r) {
        h2_t pr = __builtin_bit_cast(h2_t, gd[r]);
        e0[r] = (((int)(float)pr[0]) & 15) | (lane & 48);  // forced in-group
        e1[r] = (((int)(float)pr[1]) & 15) | (lane & 48);
        covm |= 1u << (e0[r] & 15);
        covm |= 1u << (e1[r] & 15);
    }
    const bool gok = (__all(covm == 0xFFFFu) != 0);

    // --- M0 combine machinery: partner via cndmask --------------------------
    const bool hi32 = (lane & 32) != 0;
    const bool hi16 = (lane & 16) != 0;
    u32x2_t r32 = __builtin_amdgcn_permlane32_swap((unsigned)lane, (unsigned)lane, false, false);
    const bool m32A = (__all((int)(hi32 ? r32[0] : r32[1]) == (lane ^ 32)) != 0);
    const bool m32B = (__all((int)(hi32 ? r32[1] : r32[0]) == (lane ^ 32)) != 0);
    const bool ok32 = m32A || m32B;
    const bool p32_r0 = m32A ? hi32 : !hi32;

    u32x2_t r16 = __builtin_amdgcn_permlane16_swap((unsigned)lane, (unsigned)lane, false, false);
    const bool m16A = (__all((int)(hi16 ? r16[0] : r16[1]) == (lane ^ 16)) != 0);
    const bool m16B = (__all((int)(hi16 ? r16[1] : r16[0]) == (lane ^ 16)) != 0);
    const bool ok16 = m16A || m16B;
    const bool p16_r0 = m16A ? hi16 : !hi16;

    auto partner32 = [&](float v) -> float {
        unsigned u = __builtin_bit_cast(unsigned, v);
        u32x2_t r = __builtin_amdgcn_permlane32_swap(u, u, false, false);
        return __builtin_bit_cast(float, p32_r0 ? r[0] : r[1]);
    };
    auto partner16 = [&](float v) -> float {
        unsigned u = __builtin_bit_cast(unsigned, v);
        u32x2_t r = __builtin_amdgcn_permlane16_swap(u, u, false, false);
        return __builtin_bit_cast(float, p16_r0 ? r[0] : r[1]);
    };
    auto comb4_m0 = [&](float P0, float P1, float P2, float P3) -> float {
        float Q0 = P0 + partner32(P2);
        float Q1 = P1 + partner32(P3);
        return Q0 + partner16(Q1);
    };
    auto comb4_m1 = [&](float P0, float P1, float P2, float P3) -> float {
        float Q0 = sum2(sw32(P0, P2));
        float Q1 = sum2(sw32(P1, P3));
        return sum2(sw16(Q0, Q1));
    };
    auto comb4_m2 = [&](float P0, float P1, float P2, float P3) -> float {
        float Q0 = sum2(sw32(P2, P0));
        float Q1 = sum2(sw32(P3, P1));
        return sum2(sw16(Q1, Q0));
    };

    auto ctest = [&](auto&& cf) -> bool {
        float P0 = (float)lane;
        float P1 = (float)lane + 64.0f;
        float P2 = (float)lane + 128.0f;
        float P3 = (float)lane + 192.0f;
        float T  = (float)lane + (float)(lane ^ 16) + (float)(lane ^ 32)
                 + (float)(lane ^ 48) + 384.0f;
        return __all(cf(P0, P1, P2, P3) == T) != 0;
    };

    const bool v1 = ctest(comb4_m1);
    const bool v2 = ctest(comb4_m2);
    const bool v0 = ok32 && ok16 && ctest(comb4_m0);

    if (gok && (v1 || v2 || v0)) {
        // whp[k][r]: h2 of W_hh[o_k][e(r,*)] * beta[o_k], o_k = lane^(k<<4)
        h2_t whp[4][8];
        #pragma unroll
        for (int k = 0; k < 4; ++k) {
            int o = lane ^ (k << 4);
            float bto = beta_of(hsub * (1.0f / tau[o]));
            const float* wrow = W_hh + o * HID;
            #pragma unroll
            for (int r = 0; r < 8; ++r) {
                whp[k][r] = __builtin_amdgcn_cvt_pkrtz(wrow[e0[r]] * bto,
                                                       wrow[e1[r]] * bto);
            }
        }

        auto runfast = [&](auto&& C4) {
            float h = 0.0f;
            // depth-3 cb prefetch (covers ~1000 cyc of load latency)
            float c1 = cbp[(size_t)HID * 1];
            float c2 = cbp[(size_t)HID * 2];
            float c3 = cbp[(size_t)HID * 3];
            for (int s = 1; s < SLEN; ++s) {
                float cbv = c1; c1 = c2; c2 = c3;
                int sn = (s + 3 < SLEN) ? (s + 3) : (SLEN - 1);
                c3 = cbp[(size_t)HID * sn];

                float t = fast_tanh(h);
                tp[(size_t)(s - 1) * HID] = (__fp16)t;   // t_{s-1} (coalesced)
                unsigned g[8];
                gatherG(t, g);
                float P[4];
                #pragma unroll
                for (int k = 0; k < 4; ++k) {            // 2 chains x depth 4
                    float u = (k == 0) ? cbv : 0.0f;
                    float v = 0.0f;
                    u = fdot(g[0], whp[k][0], u); v = fdot(g[1], whp[k][1], v);
                    u = fdot(g[2], whp[k][2], u); v = fdot(g[3], whp[k][3], v);
                    u = fdot(g[4], whp[k][4], u); v = fdot(g[5], whp[k][5], v);
                    u = fdot(g[6], whp[k][6], u); v = fdot(g[7], whp[k][7], v);
                    P[k] = u + v;
                }
                float f = C4(P[0], P[1], P[2], P[3]);
                h = fmaf(alpha, h, f);
            }
            tp[(size_t)(SLEN - 1) * HID] = (__fp16)fast_tanh(h);
        };

        if (v1)      runfast(comb4_m1);
        else if (v2) runfast(comb4_m2);
        else         runfast(comb4_m0);
    } else {
        // ---- fallback: LDS-broadcast matvec, same cb/t-store structure ----
        h2_t wh[HID / 2];
        {
            const float4* w4 = (const float4*)(W_hh + lane * HID);
            #pragma unroll
            for (int q = 0; q < HID / 4; ++q) {
                float4 v = w4[q];
                wh[2*q+0] = __builtin_amdgcn_cvt_pkrtz(v.x * beta, v.y * beta);
                wh[2*q+1] = __builtin_amdgcn_cvt_pkrtz(v.z * beta, v.w * beta);
            }
        }
        float h = 0.0f;
        float c1 = cbp[(size_t)HID * 1];
        float c2 = cbp[(size_t)HID * 2];
        float c3 = cbp[(size_t)HID * 3];
        for (int s = 1; s < SLEN; ++s) {
            float cbv = c1; c1 = c2; c2 = c3;
            int sn = (s + 3 < SLEN) ? (s + 3) : (SLEN - 1);
            c3 = cbp[(size_t)HID * sn];

            float t = fast_tanh(h);
            tp[(size_t)(s - 1) * HID] = (__fp16)t;
            th_s[lane] = (__fp16)t;
            float a0 = cbv, a1 = 0.f, a2 = 0.f, a3 = 0.f;
            const uint4* t4 = (const uint4*)th_s;
            #pragma unroll
            for (int q = 0; q < 8; ++q) {
                uint4 r = t4[q];
                a0 = fdot(r.x, wh[4*q+0], a0);
                a1 = fdot(r.y, wh[4*q+1], a1);
                a2 = fdot(r.z, wh[4*q+2], a2);
                a3 = fdot(r.w, wh[4*q+3], a3);
            }
            float f = (a0 + a1) + (a2 + a3);
            h = fmaf(alpha, h, f);
        }
        tp[(size_t)(SLEN - 1) * HID] = (__fp16)fast_tanh(h);
    }
}

// =========================================================================
// K3: output dot, fully parallel. out[b][s] = bo + sum_i wov_i * t[b][s][i]
// =========================================================================
__global__ __launch_bounds__(256) void lnn_out_kernel(
    const __fp16* __restrict__ tws,
    const float* __restrict__ W_out,
    const float* __restrict__ b_out,
    float* __restrict__ out)
{
    const int lane = threadIdx.x & 63;
    const int wid  = blockIdx.x * 4 + (threadIdx.x >> 6);   // (b*SLEN + s)
    float t = (float)tws[(size_t)wid * HID + lane];
    float v = t * W_out[lane];
    #pragma unroll
    for (int m = 32; m >= 1; m >>= 1) v += __shfl_xor(v, m, 64);
    if (lane == 0) out[wid] = v + b_out[0];
}

// =========================================================================
// Fallback (no/small workspace): r12 kernel verbatim (proven 404us).
// =========================================================================
__global__ __launch_bounds__(64, 1) void lnn_ee_kernel(
    const float* __restrict__ x,
    const float* __restrict__ W_in,
    const float* __restrict__ b_in,
    const float* __restrict__ W_hh,
    const float* __restrict__ W_ih,
    const float* __restrict__ bias,
    const float* __restrict__ tau,
    const float* __restrict__ W_out,
    const float* __restrict__ b_out,
    float* __restrict__ out)
{
    const int lane = threadIdx.x;
    const int b    = blockIdx.x;

    __shared__ float  ldsx[SLEN * INF];
    __shared__ __fp16 th_s[HID];

    {
        const float4* g4 = (const float4*)(x + (size_t)b * SLEN * INF);
        float4* l4 = (float4*)ldsx;
        #pragma unroll 8
        for (int it = lane; it < SLEN * INF / 4; it += 64) l4[it] = g4[it];
    }

    const float rtau = 1.0f / tau[lane];

    float Wc[INF];
    #pragma unroll
    for (int k = 0; k < INF; ++k) Wc[k] = 0.0f;
    float bcomb = 0.0f;
    for (int j = 0; j < HID; ++j) {
        float wij = W_ih[lane * HID + j];
        bcomb = fmaf(wij, b_in[j], bcomb);
        #pragma unroll
        for (int k = 0; k < INF; ++k) Wc[k] = fmaf(wij, W_in[j * INF + k], Wc[k]);
    }
    const float cbase = bcomb + bias[lane];
    const float bo    = b_out[0];

    const float hsub  = 1.0f / 1023.0f;
    const float beta  = beta_of(hsub * rtau);
    const float alpha = 1.0f - beta;

    float cb = 0.0f;

    float* orow = out + (size_t)b * SLEN;
    const float4* lx4 = (const float4*)ldsx;

    auto proj = [&](const float4& p0, const float4& p1,
                    const float4& p2, const float4& p3) -> float {
        float cA = fmaf(p0.x, Wc[0], fmaf(p0.y, Wc[1],
                   fmaf(p0.z, Wc[2], fmaf(p0.w, Wc[3], cbase))));
        float cB = fmaf(p1.x, Wc[4], fmaf(p1.y, Wc[5],
                   fmaf(p1.z, Wc[6], p1.w * Wc[7])));
        float cC = fmaf(p2.x, Wc[8], fmaf(p2.y, Wc[9],
                   fmaf(p2.z, Wc[10], p2.w * Wc[11])));
        float cD = fmaf(p3.x, Wc[12], fmaf(p3.y, Wc[13],
                   fmaf(p3.z, Wc[14], p3.w * Wc[15])));
        return ((cA + cB) + (cC + cD)) * beta;
    };

    unsigned gd[8];
    gatherG((float)lane, gd);
    int e0[8], e1[8];
    unsigned covm = 0;
    #pragma unroll
    for (int r = 0; r < 8; ++r) {
        h2_t pr = __builtin_bit_cast(h2_t, gd[r]);
        e0[r] = (((int)(float)pr[0]) & 15) | (lane & 48);
        e1[r] = (((int)(float)pr[1]) & 15) | (lane & 48);
        covm |= 1u << (e0[r] & 15);
        covm |= 1u << (e1[r] & 15);
    }
    const bool gok = (__all(covm == 0xFFFFu) != 0);

    const bool hi32 = (lane & 32) != 0;
    const bool hi16 = (lane & 16) != 0;
    u32x2_t r32 = __builtin_amdgcn_permlane32_swap((unsigned)lane, (unsigned)lane, false, false);
    const bool m32A = (__all((int)(hi32 ? r32[0] : r32[1]) == (lane ^ 32)) != 0);
    const bool m32B = (__all((int)(hi32 ? r32[1] : r32[0]) == (lane ^ 32)) != 0);
    const bool ok32 = m32A || m32B;
    const bool p32_r0 = m32A ? hi32 : !hi32;

    u32x2_t r16 = __builtin_amdgcn_permlane16_swap((unsigned)lane, (unsigned)lane, false, false);
    const bool m16A = (__all((int)(hi16 ? r16[0] : r16[1]) == (lane ^ 16)) != 0);
    const bool m16B = (__all((int)(hi16 ? r16[1] : r16[0]) == (lane ^ 16)) != 0);
    const bool ok16 = m16A || m16B;
    const bool p16_r0 = m16A ? hi16 : !hi16;

    auto partner32 = [&](float v) -> float {
        unsigned u = __builtin_bit_cast(unsigned, v);
        u32x2_t r = __builtin_amdgcn_permlane32_swap(u, u, false, false);
        return __builtin_bit_cast(float, p32_r0 ? r[0] : r[1]);
    };
    auto partner16 = [&](float v) -> float {
        unsigned u = __builtin_bit_cast(unsigned, v);
        u32x2_t r = __builtin_amdgcn_permlane16_swap(u, u, false, false);
        return __builtin_bit_cast(float, p16_r0 ? r[0] : r[1]);
    };
    auto comb4_m0 = [&](float P0, float P1, float P2, float P3) -> float {
        float Q0 = P0 + partner32(P2);
        float Q1 = P1 + partner32(P3);
        return Q0 + partner16(Q1);
    };
    auto allsum_m0 = [&](float v) -> float {
        float a = v + partner32(v);
        return a + partner16(a);
    };
    auto comb4_m1 = [&](float P0, float P1, float P2, float P3) -> float {
        float Q0 = sum2(sw32(P0, P2));
        float Q1 = sum2(sw32(P1, P3));
        return sum2(sw16(Q0, Q1));
    };
    auto comb4_m2 = [&](float P0, float P1, float P2, float P3) -> float {
        float Q0 = sum2(sw32(P2, P0));
        float Q1 = sum2(sw32(P3, P1));
        return sum2(sw16(Q1, Q0));
    };
    auto allsum_m12 = [&](float v) -> float {
        float a = sum2(sw32(v, v));
        return sum2(sw16(a, a));
    };

    auto ctest = [&](auto&& cf) -> bool {
        float P0 = (float)lane;
        float P1 = (float)lane + 64.0f;
        float P2 = (float)lane + 128.0f;
        float P3 = (float)lane + 192.0f;
        float T  = (float)lane + (float)(lane ^ 16) + (float)(lane ^ 32)
                 + (float)(lane ^ 48) + 384.0f;
        return __all(cf(P0, P1, P2, P3) == T) != 0;
    };
    auto atest = [&](auto&& af) -> bool {
        float T = (float)lane + (float)(lane ^ 16) + (float)(lane ^ 32)
                + (float)(lane ^ 48);
        return __all(af((float)lane) == T) != 0;
    };

    const bool v1 = ctest(comb4_m1) && atest(allsum_m12);
    const bool v2 = ctest(comb4_m2) && atest(allsum_m12);
    const bool v0 = ok32 && ok16 && ctest(comb4_m0) && atest(allsum_m0);

    __syncthreads();

    if (gok && (v1 || v2 || v0)) {
        h2_t whp[4][8];
        #pragma unroll
        for (int k = 0; k < 4; ++k) {
            int o = lane ^ (k << 4);
            float bto = beta_of(hsub * (1.0f / tau[o]));
            const float* wrow = W_hh + o * HID;
            #pragma unroll
            for (int r = 0; r < 8; ++r) {
                whp[k][r] = __builtin_amdgcn_cvt_pkrtz(wrow[e0[r]] * bto,
                                                       wrow[e1[r]] * bto);
            }
        }
        h2_t wovp[8];
        #pragma unroll
        for (int r = 0; r < 8; ++r)
            wovp[r] = __builtin_amdgcn_cvt_pkrtz(W_out[e0[r]], W_out[e1[r]]);

        auto runfast = [&](auto&& C4, auto&& AS) {
            auto eval_out = [&](float y, float& os) -> float {
                float t = fast_tanh(y);
                unsigned g[8];
                gatherG(t, g);
                float P[4];
                #pragma unroll
                for (int k = 0; k < 4; ++k) {
                    float u = (k == 0) ? cb : 0.0f;
                    float v = 0.0f;
                    u = fdot(g[0], whp[k][0], u); v = fdot(g[1], whp[k][1], v);
                    u = fdot(g[2], whp[k][2], u); v = fdot(g[3], whp[k][3], v);
                    u = fdot(g[4], whp[k][4], u); v = fdot(g[5], whp[k][5], v);
                    u = fdot(g[6], whp[k][6], u); v = fdot(g[7], whp[k][7], v);
                    P[k] = u + v;
                }
                float o0 = 0.f, o1 = 0.f;
                o0 = fdot(g[0], wovp[0], o0); o1 = fdot(g[1], wovp[1], o1);
                o0 = fdot(g[2], wovp[2], o0); o1 = fdot(g[3], wovp[3], o1);
                o0 = fdot(g[4], wovp[4], o0); o1 = fdot(g[5], wovp[5], o1);
                o0 = fdot(g[6], wovp[6], o0); o1 = fdot(g[7], wovp[7], o1);
                os = AS(o0 + o1);
                return C4(P[0], P[1], P[2], P[3]);
            };

            float h = 0.0f;
            if (lane == 0) orow[0] = bo;
            float4 xp0 = lx4[4], xp1 = lx4[5], xp2 = lx4[6], xp3 = lx4[7];

            for (int s = 1; s < SLEN; ++s) {
                cb = proj(xp0, xp1, xp2, xp3);
                {
                    int sn = (s < SLEN - 1) ? (s + 1) : (SLEN - 1);
                    xp0 = lx4[sn*4+0]; xp1 = lx4[sn*4+1];
                    xp2 = lx4[sn*4+2]; xp3 = lx4[sn*4+3];
                }
                float os;
                float f = eval_out(h, os);
                if (lane == 0) orow[s - 1] = os + bo;
                h = fmaf(alpha, h, f);
            }
            {
                float t = fast_tanh(h);
                unsigned g[8];
                gatherG(t, g);
                float o0 = 0.f, o1 = 0.f;
                o0 = fdot(g[0], wovp[0], o0); o1 = fdot(g[1], wovp[1], o1);
                o0 = fdot(g[2], wovp[2], o0); o1 = fdot(g[3], wovp[3], o1);
                o0 = fdot(g[4], wovp[4], o0); o1 = fdot(g[5], wovp[5], o1);
                o0 = fdot(g[6], wovp[6], o0); o1 = fdot(g[7], wovp[7], o1);
                float of = AS(o0 + o1);
                if (lane == 0) orow[SLEN - 1] = of + bo;
            }
        };

        if (v1)      runfast(comb4_m1, allsum_m12);
        else if (v2) runfast(comb4_m2, allsum_m12);
        else         runfast(comb4_m0, allsum_m0);
    } else {
        h2_t wh[HID / 2], wov[HID / 2];
        {
            const float4* w4 = (const float4*)(W_hh + lane * HID);
            const float4* o4 = (const float4*)(W_out);
            #pragma unroll
            for (int q = 0; q < HID / 4; ++q) {
                float4 v = w4[q];
                wh[2*q+0] = __builtin_amdgcn_cvt_pkrtz(v.x * beta, v.y * beta);
                wh[2*q+1] = __builtin_amdgcn_cvt_pkrtz(v.z * beta, v.w * beta);
                float4 o = o4[q];
                wov[2*q+0] = __builtin_amdgcn_cvt_pkrtz(o.x, o.y);
                wov[2*q+1] = __builtin_amdgcn_cvt_pkrtz(o.z, o.w);
            }
        }
        auto eval_out = [&](float y, float& os) -> float {
            float t = fast_tanh(y);
            th_s[lane] = (__fp16)t;
            float a0 = cb, a1 = 0.f, a2 = 0.f, a3 = 0.f;
            float o0 = 0.f, o1 = 0.f, o2 = 0.f, o3 = 0.f;
            const uint4* t4 = (const uint4*)th_s;
            #pragma unroll
            for (int q = 0; q < 8; ++q) {
                uint4 r = t4[q];
                a0 = fdot(r.x, wh[4*q+0], a0);
                a1 = fdot(r.y, wh[4*q+1], a1);
                a2 = fdot(r.z, wh[4*q+2], a2);
                a3 = fdot(r.w, wh[4*q+3], a3);
                o0 = fdot(r.x, wov[4*q+0], o0);
                o1 = fdot(r.y, wov[4*q+1], o1);
                o2 = fdot(r.z, wov[4*q+2], o2);
                o3 = fdot(r.w, wov[4*q+3], o3);
            }
            os = (o0 + o1) + (o2 + o3);
            return (a0 + a1) + (a2 + a3);
        };

        float h = 0.0f;
        if (lane == 0) orow[0] = bo;
        float4 xp0 = lx4[4], xp1 = lx4[5], xp2 = lx4[6], xp3 = lx4[7];

        for (int s = 1; s < SLEN; ++s) {
            cb = proj(xp0, xp1, xp2, xp3);
            {
                int sn = (s < SLEN - 1) ? (s + 1) : (SLEN - 1);
                xp0 = lx4[sn*4+0]; xp1 = lx4[sn*4+1];
                xp2 = lx4[sn*4+2]; xp3 = lx4[sn*4+3];
            }
            float os;
            float f = eval_out(h, os);
            if (lane == 0) orow[s - 1] = os + bo;
            h = fmaf(alpha, h, f);
        }
        {
            float t = fast_tanh(h);
            th_s[lane] = (__fp16)t;
            float o0 = 0.f, o1 = 0.f, o2 = 0.f, o3 = 0.f;
            const uint4* t4 = (const uint4*)th_s;
            #pragma unroll
            for (int q = 0; q < 8; ++q) {
                uint4 r = t4[q];
                o0 = fdot(r.x, wov[4*q+0], o0);
                o1 = fdot(r.y, wov[4*q+1], o1);
                o2 = fdot(r.z, wov[4*q+2], o2);
                o3 = fdot(r.w, wov[4*q+3], o3);
            }
            if (lane == 0) orow[SLEN - 1] = (o0 + o1) + (o2 + o3) + bo;
        }
    }
}

extern "C" void kernel_launch(void* const* d_in, const int* in_sizes, int n_in,
                              void* d_out, int out_size, void* d_ws, size_t ws_size,
                              hipStream_t stream) {
    const float* x     = (const float*)d_in[0];
    const float* W_in  = (const float*)d_in[1];
    const float* b_in  = (const float*)d_in[2];
    const float* W_hh  = (const float*)d_in[3];
    const float* W_ih  = (const float*)d_in[4];
    const float* bias  = (const float*)d_in[5];
    const float* tau   = (const float*)d_in[6];
    const float* W_out = (const float*)d_in[7];
    const float* b_out = (const float*)d_in[8];
    float* out = (float*)d_out;

    const size_t cb_bytes = (size_t)BATCH * SLEN * HID * sizeof(float);   // 128MB
    const size_t t_bytes  = (size_t)BATCH * SLEN * HID * sizeof(__fp16);  // 64MB

    if (d_ws != nullptr && ws_size >= cb_bytes + t_bytes) {
        float*  cbw = (float*)d_ws;
        __fp16* tws = (__fp16*)((char*)d_ws + cb_bytes);
        lnn_proj_kernel<<<dim3(BATCH, 8), 256, 0, stream>>>(
            x, W_in, b_in, W_ih, bias, tau, cbw);
        lnn_chain_ws_kernel<<<BATCH, 64, 0, stream>>>(cbw, tws, W_hh, tau);
        lnn_out_kernel<<<(BATCH * SLEN) / 4, 256, 0, stream>>>(
            tws, W_out, b_out, out);
    } else {
        lnn_ee_kernel<<<BATCH, 64, 0, stream>>>(x, W_in, b_in, W_hh, W_ih,
                                                bias, tau, W_out, b_out, out);
    }
}

// Round 14
// 549.290 us; speedup vs baseline: 1.0412x; 1.0412x over previous
//
#include <hip/hip_runtime.h>

// LiquidNeuralNetwork: B=512, S=1024, IN=16, HID=64, OUT=1.
// r13 lessons: K2 (serial chain) = 290us; but K1 redid setup x4096 blocks,
// K3 launched 131k blocks, and K2's t-stores evicted cb from L3 (FETCH 65MB
// for an L3-resident buffer -> HBM-latency stalls past the depth-3 prefetch).
//
// Round 14: same 4-phase decomposition, sinks fixed:
//   K0 (1 block): Wc table (16x64) + cbase -> ws, once.
//   K1 (streaming): cb[b][s][i] from the table, ~25 inst/(b,s), bit-identical
//       fma tree to r12/r13.
//   K2 (serial): r13 chain + NONTEMPORAL t-stores (keep cb L3-resident),
//       depth-4 cb prefetch, pointer-increment addressing.
//   K3 (grid-stride, 1024 blocks): out = bo + wov . t via __shfl_xor reduce.
// ws gate -> r12 single-kernel fallback (proven 404us). Discovery-verified
// swap-combine (M0/M1/M2) + LDS-broadcast fallback kept in K2.

constexpr int HID  = 64;
constexpr int INF  = 16;
constexpr int SLEN = 1024;
constexpr int BATCH = 512;

typedef __fp16 h2_t __attribute__((ext_vector_type(2)));
typedef unsigned u32x2_t __attribute__((ext_vector_type(2)));

template<int CTRL>
__device__ __forceinline__ unsigned dppmov(unsigned v) {
    return (unsigned)__builtin_amdgcn_update_dpp(0, (int)v, CTRL, 0xF, 0xF, true);
}

__device__ __forceinline__ float fdot(unsigned a, h2_t w, float acc) {
    return __builtin_amdgcn_fdot2(__builtin_bit_cast(h2_t, a), w, acc, false);
}

__device__ __forceinline__ float fast_tanh(float x) {
    // tanh(x) = 1 - 2/(e^{2x}+1); exact limits at +/-inf, no clamp needed.
    float e = __builtin_amdgcn_exp2f(x * 2.8853900817779268f); // 2*log2(e)
    float r = __builtin_amdgcn_rcpf(e + 1.0f);
    return fmaf(-2.0f, r, 1.0f);
}

// -expm1(-z) by series, exact to ~1e-17 for z ~ 1e-3 (avoids 1-exp cancel)
__device__ __forceinline__ float beta_of(float z) {
    return z * (1.0f - z * (0.5f - z * ((1.0f/6.0f) - z * (1.0f/24.0f))));
}

// In-group all-gather: lane l ends with all 16 values of its 16-lane group
// as 8 h2 regs, lane-dependent order (discovered at setup).
__device__ __forceinline__ void gatherG(float t, unsigned g[8]) {
    unsigned th = (unsigned)__builtin_bit_cast(unsigned short, (__fp16)t);
    unsigned tp = dppmov<0xB1>(th);            // quad_perm [1,0,3,2] = ^1
    g[0] = (tp << 16) | th;                    // h2 {self, ^1}
    g[1] = dppmov<0x4E>(g[0]);                 // quad_perm [2,3,0,1] = ^2
    g[2] = dppmov<0x141>(g[0]);                // row_half_mirror = ^7
    g[3] = dppmov<0x141>(g[1]);
    g[4] = dppmov<0x128>(g[0]);                // row_ror:8 = ^8
    g[5] = dppmov<0x128>(g[1]);
    g[6] = dppmov<0x128>(g[2]);
    g[7] = dppmov<0x128>(g[3]);
}

// pair swaps: returns both modified regs (float payloads)
__device__ __forceinline__ u32x2_t sw32(float a, float b) {
    return __builtin_amdgcn_permlane32_swap(__builtin_bit_cast(unsigned, a),
                                            __builtin_bit_cast(unsigned, b),
                                            false, false);
}
__device__ __forceinline__ u32x2_t sw16(float a, float b) {
    return __builtin_amdgcn_permlane16_swap(__builtin_bit_cast(unsigned, a),
                                            __builtin_bit_cast(unsigned, b),
                                            false, false);
}
__device__ __forceinline__ float sum2(u32x2_t r) {
    return __builtin_bit_cast(float, r[0]) + __builtin_bit_cast(float, r[1]);
}

// =========================================================================
// K0: Wc table + cbase, computed once (1 block x 64 thr).
//     Same fma ordering as r12/r13 -> bit-identical cb downstream.
// =========================================================================
__global__ __launch_bounds__(64) void lnn_wc_kernel(
    const float* __restrict__ W_in,
    const float* __restrict__ b_in,
    const float* __restrict__ W_ih,
    const float* __restrict__ bias,
    float* __restrict__ wct,          // [16][64]
    float* __restrict__ cbasev)       // [64]
{
    const int lane = threadIdx.x;
    float Wc[INF];
    #pragma unroll
    for (int k = 0; k < INF; ++k) Wc[k] = 0.0f;
    float bcomb = 0.0f;
    for (int j = 0; j < HID; ++j) {
        float wij = W_ih[lane * HID + j];
        bcomb = fmaf(wij, b_in[j], bcomb);
        #pragma unroll
        for (int k = 0; k < INF; ++k) Wc[k] = fmaf(wij, W_in[j * INF + k], Wc[k]);
    }
    #pragma unroll
    for (int k = 0; k < INF; ++k) wct[k * HID + lane] = Wc[k];
    cbasev[lane] = bcomb + bias[lane];
}

// =========================================================================
// K1: streaming projection. cb[b][s][i] = beta_i*(Wc_i . x[b][s] + cbase_i)
// =========================================================================
__global__ __launch_bounds__(256) void lnn_proj_kernel(
    const float* __restrict__ x,
    const float* __restrict__ tau,
    const float* __restrict__ wct,
    const float* __restrict__ cbasev,
    float* __restrict__ cb)
{
    const int b     = blockIdx.x;
    const int sbase = blockIdx.y * 128;
    const int lane  = threadIdx.x & 63;
    const int srow  = threadIdx.x >> 6;      // 0..3

    float Wc[INF];
    #pragma unroll
    for (int k = 0; k < INF; ++k) Wc[k] = wct[k * HID + lane];
    const float cbase = cbasev[lane];
    const float hsub  = 1.0f / 1023.0f;
    const float beta  = beta_of(hsub * (1.0f / tau[lane]));

    for (int it = 0; it < 32; ++it) {
        int s = sbase + it * 4 + srow;
        const float4* xs = (const float4*)(x + ((size_t)b * SLEN + s) * INF);
        float4 p0 = xs[0], p1 = xs[1], p2 = xs[2], p3 = xs[3];
        float cA = fmaf(p0.x, Wc[0], fmaf(p0.y, Wc[1],
                   fmaf(p0.z, Wc[2], fmaf(p0.w, Wc[3], cbase))));
        float cB = fmaf(p1.x, Wc[4], fmaf(p1.y, Wc[5],
                   fmaf(p1.z, Wc[6], p1.w * Wc[7])));
        float cC = fmaf(p2.x, Wc[8], fmaf(p2.y, Wc[9],
                   fmaf(p2.z, Wc[10], p2.w * Wc[11])));
        float cD = fmaf(p3.x, Wc[12], fmaf(p3.y, Wc[13],
                   fmaf(p3.z, Wc[14], p3.w * Wc[15])));
        cb[((size_t)b * SLEN + s) * HID + lane] = ((cA + cB) + (cC + cD)) * beta;
    }
}

// =========================================================================
// K2: the serial chain. Reads cb (L3-resident), writes t via NT stores.
// =========================================================================
__global__ __launch_bounds__(64, 1) void lnn_chain_ws_kernel(
    const float* __restrict__ cb,
    __fp16* __restrict__ tws,
    const float* __restrict__ W_hh,
    const float* __restrict__ tau)
{
    const int lane = threadIdx.x;        // hidden index
    const int b    = blockIdx.x;         // batch index

    __shared__ __fp16 th_s[HID];         // fallback path only

    const float hsub  = 1.0f / 1023.0f;
    const float rtau  = 1.0f / tau[lane];
    const float beta  = beta_of(hsub * rtau);
    const float alpha = 1.0f - beta;

    const float* cbp = cb  + (size_t)b * SLEN * HID + lane;
    __fp16*      tp  = tws + (size_t)b * SLEN * HID + lane;

    // --- discovery: in-group gather order -----------------------------------
    unsigned gd[8];
    gatherG((float)lane, gd);            // payload = lane index, exact in f16
    int e0[8], e1[8];
    unsigned covm = 0;
    #pragma unroll
    for (int r = 0; r < 8; ++r) {
        h2_t pr = __builtin_bit_cast(h2_t, gd[r]);
        e0[r] = (((int)(float)pr[0]) & 15) | (lane & 48);  // forced in-group
        e1[r] = (((int)(float)pr[1]) & 15) | (lane & 48);
        covm |= 1u << (e0[r] & 15);
        covm |= 1u << (e1[r] & 15);
    }
    const bool gok = (__all(covm == 0xFFFFu) != 0);

    // --- combine machinery (M0 cndmask / M1 / M2 swap-based) ----------------
    const bool hi32 = (lane & 32) != 0;
    const bool hi16 = (lane & 16) != 0;
    u32x2_t r32 = __builtin_amdgcn_permlane32_swap((unsigned)lane, (unsigned)lane, false, false);
    const bool m32A = (__all((int)(hi32 ? r32[0] : r32[1]) == (lane ^ 32)) != 0);
    const bool m32B = (__all((int)(hi32 ? r32[1] : r32[0]) == (lane ^ 32)) != 0);
    const bool ok32 = m32A || m32B;
    const bool p32_r0 = m32A ? hi32 : !hi32;

    u32x2_t r16 = __builtin_amdgcn_permlane16_swap((unsigned)lane, (unsigned)lane, false, false);
    const bool m16A = (__all((int)(hi16 ? r16[0] : r16[1]) == (lane ^ 16)) != 0);
    const bool m16B = (__all((int)(hi16 ? r16[1] : r16[0]) == (lane ^ 16)) != 0);
    const bool ok16 = m16A || m16B;
    const bool p16_r0 = m16A ? hi16 : !hi16;

    auto partner32 = [&](float v) -> float {
        unsigned u = __builtin_bit_cast(unsigned, v);
        u32x2_t r = __builtin_amdgcn_permlane32_swap(u, u, false, false);
        return __builtin_bit_cast(float, p32_r0 ? r[0] : r[1]);
    };
    auto partner16 = [&](float v) -> float {
        unsigned u = __builtin_bit_cast(unsigned, v);
        u32x2_t r = __builtin_amdgcn_permlane16_swap(u, u, false, false);
        return __builtin_bit_cast(float, p16_r0 ? r[0] : r[1]);
    };
    auto comb4_m0 = [&](float P0, float P1, float P2, float P3) -> float {
        float Q0 = P0 + partner32(P2);
        float Q1 = P1 + partner32(P3);
        return Q0 + partner16(Q1);
    };
    auto comb4_m1 = [&](float P0, float P1, float P2, float P3) -> float {
        float Q0 = sum2(sw32(P0, P2));
        float Q1 = sum2(sw32(P1, P3));
        return sum2(sw16(Q0, Q1));
    };
    auto comb4_m2 = [&](float P0, float P1, float P2, float P3) -> float {
        float Q0 = sum2(sw32(P2, P0));
        float Q1 = sum2(sw32(P3, P1));
        return sum2(sw16(Q1, Q0));
    };

    auto ctest = [&](auto&& cf) -> bool {
        float P0 = (float)lane;
        float P1 = (float)lane + 64.0f;
        float P2 = (float)lane + 128.0f;
        float P3 = (float)lane + 192.0f;
        float T  = (float)lane + (float)(lane ^ 16) + (float)(lane ^ 32)
                 + (float)(lane ^ 48) + 384.0f;
        return __all(cf(P0, P1, P2, P3) == T) != 0;
    };

    const bool v1 = ctest(comb4_m1);
    const bool v2 = ctest(comb4_m2);
    const bool v0 = ok32 && ok16 && ctest(comb4_m0);

    if (gok && (v1 || v2 || v0)) {
        // whp[k][r]: h2 of W_hh[o_k][e(r,*)] * beta[o_k], o_k = lane^(k<<4)
        h2_t whp[4][8];
        #pragma unroll
        for (int k = 0; k < 4; ++k) {
            int o = lane ^ (k << 4);
            float bto = beta_of(hsub * (1.0f / tau[o]));
            const float* wrow = W_hh + o * HID;
            #pragma unroll
            for (int r = 0; r < 8; ++r) {
                whp[k][r] = __builtin_amdgcn_cvt_pkrtz(wrow[e0[r]] * bto,
                                                       wrow[e1[r]] * bto);
            }
        }

        auto runfast = [&](auto&& C4) {
            float h = 0.0f;
            // depth-4 cb prefetch (covers L3/HBM latency)
            float c1 = cbp[(size_t)HID * 1];
            float c2 = cbp[(size_t)HID * 2];
            float c3 = cbp[(size_t)HID * 3];
            float c4 = cbp[(size_t)HID * 4];
            unsigned short* tq = (unsigned short*)tp;
            for (int s = 1; s < SLEN; ++s) {
                float cbv = c1; c1 = c2; c2 = c3; c3 = c4;
                int sn = (s + 4 < SLEN) ? (s + 4) : (SLEN - 1);
                c4 = cbp[(size_t)HID * sn];

                float t = fast_tanh(h);
                // NT store: don't allocate t in L3 (keeps cb resident)
                __builtin_nontemporal_store(
                    __builtin_bit_cast(unsigned short, (__fp16)t), tq);
                tq += HID;
                unsigned g[8];
                gatherG(t, g);
                float P[4];
                #pragma unroll
                for (int k = 0; k < 4; ++k) {            // 2 chains x depth 4
                    float u = (k == 0) ? cbv : 0.0f;
                    float v = 0.0f;
                    u = fdot(g[0], whp[k][0], u); v = fdot(g[1], whp[k][1], v);
                    u = fdot(g[2], whp[k][2], u); v = fdot(g[3], whp[k][3], v);
                    u = fdot(g[4], whp[k][4], u); v = fdot(g[5], whp[k][5], v);
                    u = fdot(g[6], whp[k][6], u); v = fdot(g[7], whp[k][7], v);
                    P[k] = u + v;
                }
                float f = C4(P[0], P[1], P[2], P[3]);
                h = fmaf(alpha, h, f);
            }
            __builtin_nontemporal_store(
                __builtin_bit_cast(unsigned short, (__fp16)fast_tanh(h)), tq);
        };

        if (v1)      runfast(comb4_m1);
        else if (v2) runfast(comb4_m2);
        else         runfast(comb4_m0);
    } else {
        // ---- fallback: LDS-broadcast matvec, same cb/t-store structure ----
        h2_t wh[HID / 2];
        {
            const float4* w4 = (const float4*)(W_hh + lane * HID);
            #pragma unroll
            for (int q = 0; q < HID / 4; ++q) {
                float4 v = w4[q];
                wh[2*q+0] = __builtin_amdgcn_cvt_pkrtz(v.x * beta, v.y * beta);
                wh[2*q+1] = __builtin_amdgcn_cvt_pkrtz(v.z * beta, v.w * beta);
            }
        }
        float h = 0.0f;
        float c1 = cbp[(size_t)HID * 1];
        float c2 = cbp[(size_t)HID * 2];
        float c3 = cbp[(size_t)HID * 3];
        for (int s = 1; s < SLEN; ++s) {
            float cbv = c1; c1 = c2; c2 = c3;
            int sn = (s + 3 < SLEN) ? (s + 3) : (SLEN - 1);
            c3 = cbp[(size_t)HID * sn];

            float t = fast_tanh(h);
            tp[(size_t)(s - 1) * HID] = (__fp16)t;
            th_s[lane] = (__fp16)t;
            float a0 = cbv, a1 = 0.f, a2 = 0.f, a3 = 0.f;
            const uint4* t4 = (const uint4*)th_s;
            #pragma unroll
            for (int q = 0; q < 8; ++q) {
                uint4 r = t4[q];
                a0 = fdot(r.x, wh[4*q+0], a0);
                a1 = fdot(r.y, wh[4*q+1], a1);
                a2 = fdot(r.z, wh[4*q+2], a2);
                a3 = fdot(r.w, wh[4*q+3], a3);
            }
            float f = (a0 + a1) + (a2 + a3);
            h = fmaf(alpha, h, f);
        }
        tp[(size_t)(SLEN - 1) * HID] = (__fp16)fast_tanh(h);
    }
}

// =========================================================================
// K3: output dot, grid-stride. out[wid] = bo + sum_i wov_i * t[wid][i]
// =========================================================================
__global__ __launch_bounds__(256) void lnn_out_kernel(
    const __fp16* __restrict__ tws,
    const float* __restrict__ W_out,
    const float* __restrict__ b_out,
    float* __restrict__ out)
{
    const int lane = threadIdx.x & 63;
    const int wv   = blockIdx.x * 4 + (threadIdx.x >> 6);
    const int nw   = gridDim.x * 4;
    const float wo = W_out[lane];
    const float bo = b_out[0];
    for (int wid = wv; wid < BATCH * SLEN; wid += nw) {
        float t = (float)tws[(size_t)wid * HID + lane];
        float v = t * wo;
        #pragma unroll
        for (int m = 32; m >= 1; m >>= 1) v += __shfl_xor(v, m, 64);
        if (lane == 0) out[wid] = v + bo;
    }
}

// =========================================================================
// Fallback (no/small workspace): r12 kernel verbatim (proven 404us).
// =========================================================================
__global__ __launch_bounds__(64, 1) void lnn_ee_kernel(
    const float* __restrict__ x,
    const float* __restrict__ W_in,
    const float* __restrict__ b_in,
    const float* __restrict__ W_hh,
    const float* __restrict__ W_ih,
    const float* __restrict__ bias,
    const float* __restrict__ tau,
    const float* __restrict__ W_out,
    const float* __restrict__ b_out,
    float* __restrict__ out)
{
    const int lane = threadIdx.x;
    const int b    = blockIdx.x;

    __shared__ float  ldsx[SLEN * INF];
    __shared__ __fp16 th_s[HID];

    {
        const float4* g4 = (const float4*)(x + (size_t)b * SLEN * INF);
        float4* l4 = (float4*)ldsx;
        #pragma unroll 8
        for (int it = lane; it < SLEN * INF / 4; it += 64) l4[it] = g4[it];
    }

    const float rtau = 1.0f / tau[lane];

    float Wc[INF];
    #pragma unroll
    for (int k = 0; k < INF; ++k) Wc[k] = 0.0f;
    float bcomb = 0.0f;
    for (int j = 0; j < HID; ++j) {
        float wij = W_ih[lane * HID + j];
        bcomb = fmaf(wij, b_in[j], bcomb);
        #pragma unroll
        for (int k = 0; k < INF; ++k) Wc[k] = fmaf(wij, W_in[j * INF + k], Wc[k]);
    }
    const float cbase = bcomb + bias[lane];
    const float bo    = b_out[0];

    const float hsub  = 1.0f / 1023.0f;
    const float beta  = beta_of(hsub * rtau);
    const float alpha = 1.0f - beta;

    float cb = 0.0f;

    float* orow = out + (size_t)b * SLEN;
    const float4* lx4 = (const float4*)ldsx;

    auto proj = [&](const float4& p0, const float4& p1,
                    const float4& p2, const float4& p3) -> float {
        float cA = fmaf(p0.x, Wc[0], fmaf(p0.y, Wc[1],
                   fmaf(p0.z, Wc[2], fmaf(p0.w, Wc[3], cbase))));
        float cB = fmaf(p1.x, Wc[4], fmaf(p1.y, Wc[5],
                   fmaf(p1.z, Wc[6], p1.w * Wc[7])));
        float cC = fmaf(p2.x, Wc[8], fmaf(p2.y, Wc[9],
                   fmaf(p2.z, Wc[10], p2.w * Wc[11])));
        float cD = fmaf(p3.x, Wc[12], fmaf(p3.y, Wc[13],
                   fmaf(p3.z, Wc[14], p3.w * Wc[15])));
        return ((cA + cB) + (cC + cD)) * beta;
    };

    unsigned gd[8];
    gatherG((float)lane, gd);
    int e0[8], e1[8];
    unsigned covm = 0;
    #pragma unroll
    for (int r = 0; r < 8; ++r) {
        h2_t pr = __builtin_bit_cast(h2_t, gd[r]);
        e0[r] = (((int)(float)pr[0]) & 15) | (lane & 48);
        e1[r] = (((int)(float)pr[1]) & 15) | (lane & 48);
        covm |= 1u << (e0[r] & 15);
        covm |= 1u << (e1[r] & 15);
    }
    const bool gok = (__all(covm == 0xFFFFu) != 0);

    const bool hi32 = (lane & 32) != 0;
    const bool hi16 = (lane & 16) != 0;
    u32x2_t r32 = __builtin_amdgcn_permlane32_swap((unsigned)lane, (unsigned)lane, false, false);
    const bool m32A = (__all((int)(hi32 ? r32[0] : r32[1]) == (lane ^ 32)) != 0);
    const bool m32B = (__all((int)(hi32 ? r32[1] : r32[0]) == (lane ^ 32)) != 0);
    const bool ok32 = m32A || m32B;
    const bool p32_r0 = m32A ? hi32 : !hi32;

    u32x2_t r16 = __builtin_amdgcn_permlane16_swap((unsigned)lane, (unsigned)lane, false, false);
    const bool m16A = (__all((int)(hi16 ? r16[0] : r16[1]) == (lane ^ 16)) != 0);
    const bool m16B = (__all((int)(hi16 ? r16[1] : r16[0]) == (lane ^ 16)) != 0);
    const bool ok16 = m16A || m16B;
    const bool p16_r0 = m16A ? hi16 : !hi16;

    auto partner32 = [&](float v) -> float {
        unsigned u = __builtin_bit_cast(unsigned, v);
        u32x2_t r = __builtin_amdgcn_permlane32_swap(u, u, false, false);
        return __builtin_bit_cast(float, p32_r0 ? r[0] : r[1]);
    };
    auto partner16 = [&](float v) -> float {
        unsigned u = __builtin_bit_cast(unsigned, v);
        u32x2_t r = __builtin_amdgcn_permlane16_swap(u, u, false, false);
        return __builtin_bit_cast(float, p16_r0 ? r[0] : r[1]);
    };
    auto comb4_m0 = [&](float P0, float P1, float P2, float P3) -> float {
        float Q0 = P0 + partner32(P2);
        float Q1 = P1 + partner32(P3);
        return Q0 + partner16(Q1);
    };
    auto allsum_m0 = [&](float v) -> float {
        float a = v + partner32(v);
        return a + partner16(a);
    };
    auto comb4_m1 = [&](float P0, float P1, float P2, float P3) -> float {
        float Q0 = sum2(sw32(P0, P2));
        float Q1 = sum2(sw32(P1, P3));
        return sum2(sw16(Q0, Q1));
    };
    auto comb4_m2 = [&](float P0, float P1, float P2, float P3) -> float {
        float Q0 = sum2(sw32(P2, P0));
        float Q1 = sum2(sw32(P3, P1));
        return sum2(sw16(Q1, Q0));
    };
    auto allsum_m12 = [&](float v) -> float {
        float a = sum2(sw32(v, v));
        return sum2(sw16(a, a));
    };

    auto ctest = [&](auto&& cf) -> bool {
        float P0 = (float)lane;
        float P1 = (float)lane + 64.0f;
        float P2 = (float)lane + 128.0f;
        float P3 = (float)lane + 192.0f;
        float T  = (float)lane + (float)(lane ^ 16) + (float)(lane ^ 32)
                 + (float)(lane ^ 48) + 384.0f;
        return __all(cf(P0, P1, P2, P3) == T) != 0;
    };
    auto atest = [&](auto&& af) -> bool {
        float T = (float)lane + (float)(lane ^ 16) + (float)(lane ^ 32)
                + (float)(lane ^ 48);
        return __all(af((float)lane) == T) != 0;
    };

    const bool v1 = ctest(comb4_m1) && atest(allsum_m12);
    const bool v2 = ctest(comb4_m2) && atest(allsum_m12);
    const bool v0 = ok32 && ok16 && ctest(comb4_m0) && atest(allsum_m0);

    __syncthreads();

    if (gok && (v1 || v2 || v0)) {
        h2_t whp[4][8];
        #pragma unroll
        for (int k = 0; k < 4; ++k) {
            int o = lane ^ (k << 4);
            float bto = beta_of(hsub * (1.0f / tau[o]));
            const float* wrow = W_hh + o * HID;
            #pragma unroll
            for (int r = 0; r < 8; ++r) {
                whp[k][r] = __builtin_amdgcn_cvt_pkrtz(wrow[e0[r]] * bto,
                                                       wrow[e1[r]] * bto);
            }
        }
        h2_t wovp[8];
        #pragma unroll
        for (int r = 0; r < 8; ++r)
            wovp[r] = __builtin_amdgcn_cvt_pkrtz(W_out[e0[r]], W_out[e1[r]]);

        auto runfast = [&](auto&& C4, auto&& AS) {
            auto eval_out = [&](float y, float& os) -> float {
                float t = fast_tanh(y);
                unsigned g[8];
                gatherG(t, g);
                float P[4];
                #pragma unroll
                for (int k = 0; k < 4; ++k) {
                    float u = (k == 0) ? cb : 0.0f;
                    float v = 0.0f;
                    u = fdot(g[0], whp[k][0], u); v = fdot(g[1], whp[k][1], v);
                    u = fdot(g[2], whp[k][2], u); v = fdot(g[3], whp[k][3], v);
                    u = fdot(g[4], whp[k][4], u); v = fdot(g[5], whp[k][5], v);
                    u = fdot(g[6], whp[k][6], u); v = fdot(g[7], whp[k][7], v);
                    P[k] = u + v;
                }
                float o0 = 0.f, o1 = 0.f;
                o0 = fdot(g[0], wovp[0], o0); o1 = fdot(g[1], wovp[1], o1);
                o0 = fdot(g[2], wovp[2], o0); o1 = fdot(g[3], wovp[3], o1);
                o0 = fdot(g[4], wovp[4], o0); o1 = fdot(g[5], wovp[5], o1);
                o0 = fdot(g[6], wovp[6], o0); o1 = fdot(g[7], wovp[7], o1);
                os = AS(o0 + o1);
                return C4(P[0], P[1], P[2], P[3]);
            };

            float h = 0.0f;
            if (lane == 0) orow[0] = bo;
            float4 xp0 = lx4[4], xp1 = lx4[5], xp2 = lx4[6], xp3 = lx4[7];

            for (int s = 1; s < SLEN; ++s) {
                cb = proj(xp0, xp1, xp2, xp3);
                {
                    int sn = (s < SLEN - 1) ? (s + 1) : (SLEN - 1);
                    xp0 = lx4[sn*4+0]; xp1 = lx4[sn*4+1];
                    xp2 = lx4[sn*4+2]; xp3 = lx4[sn*4+3];
                }
                float os;
                float f = eval_out(h, os);
                if (lane == 0) orow[s - 1] = os + bo;
                h = fmaf(alpha, h, f);
            }
            {
                float t = fast_tanh(h);
                unsigned g[8];
                gatherG(t, g);
                float o0 = 0.f, o1 = 0.f;
                o0 = fdot(g[0], wovp[0], o0); o1 = fdot(g[1], wovp[1], o1);
                o0 = fdot(g[2], wovp[2], o0); o1 = fdot(g[3], wovp[3], o1);
                o0 = fdot(g[4], wovp[4], o0); o1 = fdot(g[5], wovp[5], o1);
                o0 = fdot(g[6], wovp[6], o0); o1 = fdot(g[7], wovp[7], o1);
                float of = AS(o0 + o1);
                if (lane == 0) orow[SLEN - 1] = of + bo;
            }
        };

        if (v1)      runfast(comb4_m1, allsum_m12);
        else if (v2) runfast(comb4_m2, allsum_m12);
        else         runfast(comb4_m0, allsum_m0);
    } else {
        h2_t wh[HID / 2], wov[HID / 2];
        {
            const float4* w4 = (const float4*)(W_hh + lane * HID);
            const float4* o4 = (const float4*)(W_out);
            #pragma unroll
            for (int q = 0; q < HID / 4; ++q) {
                float4 v = w4[q];
                wh[2*q+0] = __builtin_amdgcn_cvt_pkrtz(v.x * beta, v.y * beta);
                wh[2*q+1] = __builtin_amdgcn_cvt_pkrtz(v.z * beta, v.w * beta);
                float4 o = o4[q];
                wov[2*q+0] = __builtin_amdgcn_cvt_pkrtz(o.x, o.y);
                wov[2*q+1] = __builtin_amdgcn_cvt_pkrtz(o.z, o.w);
            }
        }
        auto eval_out = [&](float y, float& os) -> float {
            float t = fast_tanh(y);
            th_s[lane] = (__fp16)t;
            float a0 = cb, a1 = 0.f, a2 = 0.f, a3 = 0.f;
            float o0 = 0.f, o1 = 0.f, o2 = 0.f, o3 = 0.f;
            const uint4* t4 = (const uint4*)th_s;
            #pragma unroll
            for (int q = 0; q < 8; ++q) {
                uint4 r = t4[q];
                a0 = fdot(r.x, wh[4*q+0], a0);
                a1 = fdot(r.y, wh[4*q+1], a1);
                a2 = fdot(r.z, wh[4*q+2], a2);
                a3 = fdot(r.w, wh[4*q+3], a3);
                o0 = fdot(r.x, wov[4*q+0], o0);
                o1 = fdot(r.y, wov[4*q+1], o1);
                o2 = fdot(r.z, wov[4*q+2], o2);
                o3 = fdot(r.w, wov[4*q+3], o3);
            }
            os = (o0 + o1) + (o2 + o3);
            return (a0 + a1) + (a2 + a3);
        };

        float h = 0.0f;
        if (lane == 0) orow[0] = bo;
        float4 xp0 = lx4[4], xp1 = lx4[5], xp2 = lx4[6], xp3 = lx4[7];

        for (int s = 1; s < SLEN; ++s) {
            cb = proj(xp0, xp1, xp2, xp3);
            {
                int sn = (s < SLEN - 1) ? (s + 1) : (SLEN - 1);
                xp0 = lx4[sn*4+0]; xp1 = lx4[sn*4+1];
                xp2 = lx4[sn*4+2]; xp3 = lx4[sn*4+3];
            }
            float os;
            float f = eval_out(h, os);
            if (lane == 0) orow[s - 1] = os + bo;
            h = fmaf(alpha, h, f);
        }
        {
            float t = fast_tanh(h);
            th_s[lane] = (__fp16)t;
            float o0 = 0.f, o1 = 0.f, o2 = 0.f, o3 = 0.f;
            const uint4* t4 = (const uint4*)th_s;
            #pragma unroll
            for (int q = 0; q < 8; ++q) {
                uint4 r = t4[q];
                o0 = fdot(r.x, wov[4*q+0], o0);
                o1 = fdot(r.y, wov[4*q+1], o1);
                o2 = fdot(r.z, wov[4*q+2], o2);
                o3 = fdot(r.w, wov[4*q+3], o3);
            }
            if (lane == 0) orow[SLEN - 1] = (o0 + o1) + (o2 + o3) + bo;
        }
    }
}

extern "C" void kernel_launch(void* const* d_in, const int* in_sizes, int n_in,
                              void* d_out, int out_size, void* d_ws, size_t ws_size,
                              hipStream_t stream) {
    const float* x     = (const float*)d_in[0];
    const float* W_in  = (const float*)d_in[1];
    const float* b_in  = (const float*)d_in[2];
    const float* W_hh  = (const float*)d_in[3];
    const float* W_ih  = (const float*)d_in[4];
    const float* bias  = (const float*)d_in[5];
    const float* tau   = (const float*)d_in[6];
    const float* W_out = (const float*)d_in[7];
    const float* b_out = (const float*)d_in[8];
    float* out = (float*)d_out;

    const size_t wct_off   = 0;                                  // 4 KB
    const size_t cbase_off = 4096;                               // 256 B
    const size_t cb_off    = 8192;
    const size_t cb_bytes  = (size_t)BATCH * SLEN * HID * sizeof(float);   // 128MB
    const size_t t_off     = cb_off + cb_bytes;
    const size_t t_bytes   = (size_t)BATCH * SLEN * HID * sizeof(__fp16);  // 64MB

    if (d_ws != nullptr && ws_size >= t_off + t_bytes) {
        float*  wct    = (float*)((char*)d_ws + wct_off);
        float*  cbasev = (float*)((char*)d_ws + cbase_off);
        float*  cbw    = (float*)((char*)d_ws + cb_off);
        __fp16* tws    = (__fp16*)((char*)d_ws + t_off);
        lnn_wc_kernel<<<1, 64, 0, stream>>>(W_in, b_in, W_ih, bias, wct, cbasev);
        lnn_proj_kernel<<<dim3(BATCH, 8), 256, 0, stream>>>(
            x, tau, wct, cbasev, cbw);
        lnn_chain_ws_kernel<<<BATCH, 64, 0, stream>>>(cbw, tws, W_hh, tau);
        lnn_out_kernel<<<1024, 256, 0, stream>>>(tws, W_out, b_out, out);
    } else {
        lnn_ee_kernel<<<BATCH, 64, 0, stream>>>(x, W_in, b_in, W_hh, W_ih,
                                                bias, tau, W_out, b_out, out);
    }
}

// Round 15
// 406.347 us; speedup vs baseline: 1.4075x; 1.3518x over previous
//
#include <hip/hip_runtime.h>

// LiquidNeuralNetwork: B=512, S=1024, IN=16, HID=64, OUT=1.
// r12: single kernel, proj+odot on the serial wave -> 345us dispatch.
// r13/r14: proj/odot moved to separate kernels via 192MB of HBM workspace:
// serial K2 = 290us but transport+launches cost ~260us -> net loss.
//
// Round 15: SAME decomposition, ZERO transport. One kernel, 256 thr (4
// waves), 8 chunks of 128 steps:
//   proj  (all 4 waves): cbL[128][64] (f32, LDS) for the chunk  (~2.5us)
//   serial (wave 0):     128 steps; cb = LDS read (no HBM latency), t ->
//                        tL[128][64] (f16, LDS); ~60 inst/step
//   odot  (all 4 waves): out = bo + wov . tL via __shfl_xor reduce
// LDS 48.6KB -> 2 blocks/CU (512 blocks in one round). No workspace.
// expEuler (r12-proven): h <- alpha*h + beta*G(h); absmax floor is the f16
// weight quantization (bit-identical across r10-r14 integrator changes).
// Discovery-verified swap-combine (M0/M1/M2) + LDS-broadcast fallback kept
// inside wave 0's serial phase; barriers only at block-uniform points.

constexpr int HID  = 64;
constexpr int INF  = 16;
constexpr int SLEN = 1024;
constexpr int BATCH = 512;
constexpr int CH   = 128;            // steps per chunk
constexpr int NCH  = SLEN / CH;      // 8

typedef __fp16 h2_t __attribute__((ext_vector_type(2)));
typedef unsigned u32x2_t __attribute__((ext_vector_type(2)));

template<int CTRL>
__device__ __forceinline__ unsigned dppmov(unsigned v) {
    return (unsigned)__builtin_amdgcn_update_dpp(0, (int)v, CTRL, 0xF, 0xF, true);
}

__device__ __forceinline__ float fdot(unsigned a, h2_t w, float acc) {
    return __builtin_amdgcn_fdot2(__builtin_bit_cast(h2_t, a), w, acc, false);
}

__device__ __forceinline__ float fast_tanh(float x) {
    // tanh(x) = 1 - 2/(e^{2x}+1); exact limits at +/-inf, no clamp needed.
    float e = __builtin_amdgcn_exp2f(x * 2.8853900817779268f); // 2*log2(e)
    float r = __builtin_amdgcn_rcpf(e + 1.0f);
    return fmaf(-2.0f, r, 1.0f);
}

// -expm1(-z) by series, exact to ~1e-17 for z ~ 1e-3 (avoids 1-exp cancel)
__device__ __forceinline__ float beta_of(float z) {
    return z * (1.0f - z * (0.5f - z * ((1.0f/6.0f) - z * (1.0f/24.0f))));
}

// In-group all-gather: lane l ends with all 16 values of its 16-lane group
// as 8 h2 regs, lane-dependent order (discovered at setup).
__device__ __forceinline__ void gatherG(float t, unsigned g[8]) {
    unsigned th = (unsigned)__builtin_bit_cast(unsigned short, (__fp16)t);
    unsigned tp = dppmov<0xB1>(th);            // quad_perm [1,0,3,2] = ^1
    g[0] = (tp << 16) | th;                    // h2 {self, ^1}
    g[1] = dppmov<0x4E>(g[0]);                 // quad_perm [2,3,0,1] = ^2
    g[2] = dppmov<0x141>(g[0]);                // row_half_mirror = ^7
    g[3] = dppmov<0x141>(g[1]);
    g[4] = dppmov<0x128>(g[0]);                // row_ror:8 = ^8
    g[5] = dppmov<0x128>(g[1]);
    g[6] = dppmov<0x128>(g[2]);
    g[7] = dppmov<0x128>(g[3]);
}

// pair swaps: returns both modified regs (float payloads)
__device__ __forceinline__ u32x2_t sw32(float a, float b) {
    return __builtin_amdgcn_permlane32_swap(__builtin_bit_cast(unsigned, a),
                                            __builtin_bit_cast(unsigned, b),
                                            false, false);
}
__device__ __forceinline__ u32x2_t sw16(float a, float b) {
    return __builtin_amdgcn_permlane16_swap(__builtin_bit_cast(unsigned, a),
                                            __builtin_bit_cast(unsigned, b),
                                            false, false);
}
__device__ __forceinline__ float sum2(u32x2_t r) {
    return __builtin_bit_cast(float, r[0]) + __builtin_bit_cast(float, r[1]);
}

__global__ __launch_bounds__(256, 1) void lnn_fused_kernel(
    const float* __restrict__ x,
    const float* __restrict__ W_in,
    const float* __restrict__ b_in,
    const float* __restrict__ W_hh,
    const float* __restrict__ W_ih,
    const float* __restrict__ bias,
    const float* __restrict__ tau,
    const float* __restrict__ W_out,
    const float* __restrict__ b_out,
    float* __restrict__ out)
{
    const int tid  = threadIdx.x;
    const int lane = tid & 63;           // hidden index
    const int wid  = tid >> 6;           // wave id 0..3
    const int b    = blockIdx.x;         // batch index

    __shared__ float  cbL[CH + 1][HID];  // +1 row: OOB-safe prefetch
    __shared__ __fp16 tL[CH][HID];
    __shared__ __fp16 th_s[HID];         // fallback broadcast buffer

    // --- per-lane setup (all waves redundantly; ~3us once per block) -------
    float Wc[INF];
    #pragma unroll
    for (int k = 0; k < INF; ++k) Wc[k] = 0.0f;
    float bcomb = 0.0f;
    for (int j = 0; j < HID; ++j) {
        float wij = W_ih[lane * HID + j];
        bcomb = fmaf(wij, b_in[j], bcomb);
        #pragma unroll
        for (int k = 0; k < INF; ++k) Wc[k] = fmaf(wij, W_in[j * INF + k], Wc[k]);
    }
    const float cbase = bcomb + bias[lane];
    const float bo    = b_out[0];
    const float wo    = W_out[lane];

    const float hsub  = 1.0f / 1023.0f;
    const float rtau  = 1.0f / tau[lane];
    const float beta  = beta_of(hsub * rtau);
    const float alpha = 1.0f - beta;

    // --- discovery: in-group gather order (same result in every wave) ------
    unsigned gd[8];
    gatherG((float)lane, gd);
    int e0[8], e1[8];
    unsigned covm = 0;
    #pragma unroll
    for (int r = 0; r < 8; ++r) {
        h2_t pr = __builtin_bit_cast(h2_t, gd[r]);
        e0[r] = (((int)(float)pr[0]) & 15) | (lane & 48);
        e1[r] = (((int)(float)pr[1]) & 15) | (lane & 48);
        covm |= 1u << (e0[r] & 15);
        covm |= 1u << (e1[r] & 15);
    }
    const bool gok = (__all(covm == 0xFFFFu) != 0);

    const bool hi32 = (lane & 32) != 0;
    const bool hi16 = (lane & 16) != 0;
    u32x2_t r32 = __builtin_amdgcn_permlane32_swap((unsigned)lane, (unsigned)lane, false, false);
    const bool m32A = (__all((int)(hi32 ? r32[0] : r32[1]) == (lane ^ 32)) != 0);
    const bool m32B = (__all((int)(hi32 ? r32[1] : r32[0]) == (lane ^ 32)) != 0);
    const bool ok32 = m32A || m32B;
    const bool p32_r0 = m32A ? hi32 : !hi32;

    u32x2_t r16 = __builtin_amdgcn_permlane16_swap((unsigned)lane, (unsigned)lane, false, false);
    const bool m16A = (__all((int)(hi16 ? r16[0] : r16[1]) == (lane ^ 16)) != 0);
    const bool m16B = (__all((int)(hi16 ? r16[1] : r16[0]) == (lane ^ 16)) != 0);
    const bool ok16 = m16A || m16B;
    const bool p16_r0 = m16A ? hi16 : !hi16;

    auto partner32 = [&](float v) -> float {
        unsigned u = __builtin_bit_cast(unsigned, v);
        u32x2_t r = __builtin_amdgcn_permlane32_swap(u, u, false, false);
        return __builtin_bit_cast(float, p32_r0 ? r[0] : r[1]);
    };
    auto partner16 = [&](float v) -> float {
        unsigned u = __builtin_bit_cast(unsigned, v);
        u32x2_t r = __builtin_amdgcn_permlane16_swap(u, u, false, false);
        return __builtin_bit_cast(float, p16_r0 ? r[0] : r[1]);
    };
    auto comb4_m0 = [&](float P0, float P1, float P2, float P3) -> float {
        float Q0 = P0 + partner32(P2);
        float Q1 = P1 + partner32(P3);
        return Q0 + partner16(Q1);
    };
    auto comb4_m1 = [&](float P0, float P1, float P2, float P3) -> float {
        float Q0 = sum2(sw32(P0, P2));
        float Q1 = sum2(sw32(P1, P3));
        return sum2(sw16(Q0, Q1));
    };
    auto comb4_m2 = [&](float P0, float P1, float P2, float P3) -> float {
        float Q0 = sum2(sw32(P2, P0));
        float Q1 = sum2(sw32(P3, P1));
        return sum2(sw16(Q1, Q0));
    };

    auto ctest = [&](auto&& cf) -> bool {
        float P0 = (float)lane;
        float P1 = (float)lane + 64.0f;
        float P2 = (float)lane + 128.0f;
        float P3 = (float)lane + 192.0f;
        float T  = (float)lane + (float)(lane ^ 16) + (float)(lane ^ 32)
                 + (float)(lane ^ 48) + 384.0f;
        return __all(cf(P0, P1, P2, P3) == T) != 0;
    };

    const bool v1 = ctest(comb4_m1);
    const bool v2 = ctest(comb4_m2);
    const bool v0 = ok32 && ok16 && ctest(comb4_m0);
    const bool fast = gok && (v1 || v2 || v0);

    // --- weight tables ------------------------------------------------------
    // whp[k][r]: W_hh[o_k][e(r,*)] * beta[o_k], o_k = lane^(k<<4) (fast path)
    h2_t whp[4][8];
    #pragma unroll
    for (int k = 0; k < 4; ++k) {
        int o = lane ^ (k << 4);
        float bto = beta_of(hsub * (1.0f / tau[o]));
        const float* wrow = W_hh + o * HID;
        #pragma unroll
        for (int r = 0; r < 8; ++r) {
            whp[k][r] = __builtin_amdgcn_cvt_pkrtz(wrow[e0[r]] * bto,
                                                   wrow[e1[r]] * bto);
        }
    }
    // wh: in-order rows for the LDS-broadcast fallback
    h2_t wh[HID / 2];
    {
        const float4* w4 = (const float4*)(W_hh + lane * HID);
        #pragma unroll
        for (int q = 0; q < HID / 4; ++q) {
            float4 v = w4[q];
            wh[2*q+0] = __builtin_amdgcn_cvt_pkrtz(v.x * beta, v.y * beta);
            wh[2*q+1] = __builtin_amdgcn_cvt_pkrtz(v.z * beta, v.w * beta);
        }
    }

    // --- serial-phase bodies (wave 0 only) ----------------------------------
    float h = 0.0f;                      // meaningful in wave 0

    auto serial_fast = [&](auto&& C4, int ns) {
        float cnext = cbL[0][lane];
        for (int j = 0; j < ns; ++j) {
            float cbv = cnext;
            cnext = cbL[j + 1][lane];    // row CH is valid padding
            float t = fast_tanh(h);
            tL[j][lane] = (__fp16)t;     // slot (chunk_base + j)
            unsigned g[8];
            gatherG(t, g);
            float P[4];
            #pragma unroll
            for (int k = 0; k < 4; ++k) {     // 2 chains x depth 4
                float u = (k == 0) ? cbv : 0.0f;
                float v = 0.0f;
                u = fdot(g[0], whp[k][0], u); v = fdot(g[1], whp[k][1], v);
                u = fdot(g[2], whp[k][2], u); v = fdot(g[3], whp[k][3], v);
                u = fdot(g[4], whp[k][4], u); v = fdot(g[5], whp[k][5], v);
                u = fdot(g[6], whp[k][6], u); v = fdot(g[7], whp[k][7], v);
                P[k] = u + v;
            }
            float f = C4(P[0], P[1], P[2], P[3]);
            h = fmaf(alpha, h, f);
        }
    };
    auto serial_fb = [&](int ns) {
        float cnext = cbL[0][lane];
        for (int j = 0; j < ns; ++j) {
            float cbv = cnext;
            cnext = cbL[j + 1][lane];
            float t = fast_tanh(h);
            tL[j][lane] = (__fp16)t;
            th_s[lane] = (__fp16)t;
            float a0 = cbv, a1 = 0.f, a2 = 0.f, a3 = 0.f;
            const uint4* t4 = (const uint4*)th_s;
            #pragma unroll
            for (int q = 0; q < 8; ++q) {
                uint4 r = t4[q];
                a0 = fdot(r.x, wh[4*q+0], a0);
                a1 = fdot(r.y, wh[4*q+1], a1);
                a2 = fdot(r.z, wh[4*q+2], a2);
                a3 = fdot(r.w, wh[4*q+3], a3);
            }
            float f = (a0 + a1) + (a2 + a3);
            h = fmaf(alpha, h, f);
        }
    };

    // --- chunk pipeline -----------------------------------------------------
    for (int k = 0; k < NCH; ++k) {
        // proj phase: 4 waves x 32 s-values. cbL[j] <-> s = k*CH + 1 + j.
        for (int jj = 0; jj < 32; ++jj) {
            int j = wid * 32 + jj;
            int s = k * CH + 1 + j;
            if (s > SLEN - 1) s = SLEN - 1;          // k=7,j=127: unused row
            const float4* xs = (const float4*)(x + ((size_t)b * SLEN + s) * INF);
            float4 p0 = xs[0], p1 = xs[1], p2 = xs[2], p3 = xs[3];
            float cA = fmaf(p0.x, Wc[0], fmaf(p0.y, Wc[1],
                       fmaf(p0.z, Wc[2], fmaf(p0.w, Wc[3], cbase))));
            float cB = fmaf(p1.x, Wc[4], fmaf(p1.y, Wc[5],
                       fmaf(p1.z, Wc[6], p1.w * Wc[7])));
            float cC = fmaf(p2.x, Wc[8], fmaf(p2.y, Wc[9],
                       fmaf(p2.z, Wc[10], p2.w * Wc[11])));
            float cD = fmaf(p3.x, Wc[12], fmaf(p3.y, Wc[13],
                       fmaf(p3.z, Wc[14], p3.w * Wc[15])));
            cbL[j][lane] = ((cA + cB) + (cC + cD)) * beta;
        }
        __syncthreads();

        // serial phase: wave 0. k<7: 128 steps; k=7: 127 steps + final tanh.
        if (wid == 0) {
            int ns = (k < NCH - 1) ? CH : (CH - 1);
            if (fast) {
                if (v1)      serial_fast(comb4_m1, ns);
                else if (v2) serial_fast(comb4_m2, ns);
                else         serial_fast(comb4_m0, ns);
            } else {
                serial_fb(ns);
            }
            if (k == NCH - 1) tL[CH - 1][lane] = (__fp16)fast_tanh(h);
        }
        __syncthreads();

        // odot phase: out[base+j] = bo + sum_i wov_i * tL[j][i]
        for (int jj = 0; jj < 32; ++jj) {
            int j = wid * 32 + jj;
            float t = (float)tL[j][lane];
            float v = t * wo;
            #pragma unroll
            for (int m = 32; m >= 1; m >>= 1) v += __shfl_xor(v, m, 64);
            if (lane == 0) out[(size_t)b * SLEN + k * CH + j] = v + bo;
        }
        __syncthreads();                  // tL/cbL safe to overwrite
    }
}

extern "C" void kernel_launch(void* const* d_in, const int* in_sizes, int n_in,
                              void* d_out, int out_size, void* d_ws, size_t ws_size,
                              hipStream_t stream) {
    const float* x     = (const float*)d_in[0];
    const float* W_in  = (const float*)d_in[1];
    const float* b_in  = (const float*)d_in[2];
    const float* W_hh  = (const float*)d_in[3];
    const float* W_ih  = (const float*)d_in[4];
    const float* bias  = (const float*)d_in[5];
    const float* tau   = (const float*)d_in[6];
    const float* W_out = (const float*)d_in[7];
    const float* b_out = (const float*)d_in[8];
    float* out = (float*)d_out;

    lnn_fused_kernel<<<BATCH, 256, 0, stream>>>(x, W_in, b_in, W_hh, W_ih,
                                                bias, tau, W_out, b_out, out);
}